// Round 4
// baseline (176.183 us; speedup 1.0000x reference)
//
#include <hip/hip_runtime.h>
#include <stdint.h>

#define KK 1000
#define NN 1000
#define MM 900000
#define FF 7
#define SENTINEL -9999.0f

// ---- macro repetition ------------------------------------------------------
#define R18(X) X(0) X(1) X(2) X(3) X(4) X(5) X(6) X(7) X(8) X(9) X(10) X(11) \
               X(12) X(13) X(14) X(15) X(16) X(17)
#define R36(X) R18(X) X(18) X(19) X(20) X(21) X(22) X(23) X(24) X(25) X(26) \
               X(27) X(28) X(29) X(30) X(31) X(32) X(33) X(34) X(35)

// ---------------- init: zero the packed grid (ws is poisoned 0xAA) ----------
__global__ __launch_bounds__(256) void init_grid(ulonglong2* __restrict__ g, int n2) {
    int i = blockIdx.x * 256 + threadIdx.x;
    if (i < n2) g[i] = make_ulonglong2(0ULL, 0ULL);
}

// ---------------- MLP + last-write-wins scatter -----------------------------
// No early-return: divergent CF blocked s_load scalarization of the uniform
// weight reads (R1-R3: every weight was a per-lane global_load -> VMEM-bound,
// VALUBusy 60%). Index clamp keeps the kernel straight-line; tail threads
// recompute m=MM-1 and emit an identical packed atomic (idempotent).
// Named scalars (no arrays) so register residency can't depend on SROA.
__global__ __launch_bounds__(256, 4) void mlp_scatter(
    const float* __restrict__ in,    // [F][M]
    const int*   __restrict__ idx,   // [2][M]
    const float* __restrict__ w1, const float* __restrict__ b1,   // 18x7, 18
    const float* __restrict__ w2, const float* __restrict__ b2,   // 36x18, 36
    const float* __restrict__ w3, const float* __restrict__ b3,   // 36x36, 36
    const float* __restrict__ w4, const float* __restrict__ b4,   // 1x36, 1
    unsigned long long* __restrict__ grid)                        // K*N packed
{
    int m0 = blockIdx.x * 256 + threadIdx.x;
    int m = m0 < MM ? m0 : (MM - 1);

    float x0 = in[0 * MM + m], x1 = in[1 * MM + m], x2 = in[2 * MM + m],
          x3 = in[3 * MM + m], x4 = in[4 * MM + m], x5 = in[5 * MM + m],
          x6 = in[6 * MM + m];

#define L1(o) float h1_##o; { float a = b1[o];                                 \
    a = fmaf(w1[(o)*7+0], x0, a); a = fmaf(w1[(o)*7+1], x1, a);                \
    a = fmaf(w1[(o)*7+2], x2, a); a = fmaf(w1[(o)*7+3], x3, a);                \
    a = fmaf(w1[(o)*7+4], x4, a); a = fmaf(w1[(o)*7+5], x5, a);                \
    a = fmaf(w1[(o)*7+6], x6, a); h1_##o = fmaxf(a, 0.0f); }
    R18(L1)
#undef L1

#define L2(o) float h2_##o; { float a = b2[o];                                 \
    a = fmaf(w2[(o)*18+ 0], h1_0,  a); a = fmaf(w2[(o)*18+ 1], h1_1,  a);      \
    a = fmaf(w2[(o)*18+ 2], h1_2,  a); a = fmaf(w2[(o)*18+ 3], h1_3,  a);      \
    a = fmaf(w2[(o)*18+ 4], h1_4,  a); a = fmaf(w2[(o)*18+ 5], h1_5,  a);      \
    a = fmaf(w2[(o)*18+ 6], h1_6,  a); a = fmaf(w2[(o)*18+ 7], h1_7,  a);      \
    a = fmaf(w2[(o)*18+ 8], h1_8,  a); a = fmaf(w2[(o)*18+ 9], h1_9,  a);      \
    a = fmaf(w2[(o)*18+10], h1_10, a); a = fmaf(w2[(o)*18+11], h1_11, a);      \
    a = fmaf(w2[(o)*18+12], h1_12, a); a = fmaf(w2[(o)*18+13], h1_13, a);      \
    a = fmaf(w2[(o)*18+14], h1_14, a); a = fmaf(w2[(o)*18+15], h1_15, a);      \
    a = fmaf(w2[(o)*18+16], h1_16, a); a = fmaf(w2[(o)*18+17], h1_17, a);      \
    h2_##o = fmaxf(a, 0.0f); }
    R36(L2)
#undef L2

    // Layer 3 fused with layer 4: h3 never materializes.
    float v = b4[0];
#define L34(o) { float a = b3[o];                                              \
    a = fmaf(w3[(o)*36+ 0], h2_0,  a); a = fmaf(w3[(o)*36+ 1], h2_1,  a);      \
    a = fmaf(w3[(o)*36+ 2], h2_2,  a); a = fmaf(w3[(o)*36+ 3], h2_3,  a);      \
    a = fmaf(w3[(o)*36+ 4], h2_4,  a); a = fmaf(w3[(o)*36+ 5], h2_5,  a);      \
    a = fmaf(w3[(o)*36+ 6], h2_6,  a); a = fmaf(w3[(o)*36+ 7], h2_7,  a);      \
    a = fmaf(w3[(o)*36+ 8], h2_8,  a); a = fmaf(w3[(o)*36+ 9], h2_9,  a);      \
    a = fmaf(w3[(o)*36+10], h2_10, a); a = fmaf(w3[(o)*36+11], h2_11, a);      \
    a = fmaf(w3[(o)*36+12], h2_12, a); a = fmaf(w3[(o)*36+13], h2_13, a);      \
    a = fmaf(w3[(o)*36+14], h2_14, a); a = fmaf(w3[(o)*36+15], h2_15, a);      \
    a = fmaf(w3[(o)*36+16], h2_16, a); a = fmaf(w3[(o)*36+17], h2_17, a);      \
    a = fmaf(w3[(o)*36+18], h2_18, a); a = fmaf(w3[(o)*36+19], h2_19, a);      \
    a = fmaf(w3[(o)*36+20], h2_20, a); a = fmaf(w3[(o)*36+21], h2_21, a);      \
    a = fmaf(w3[(o)*36+22], h2_22, a); a = fmaf(w3[(o)*36+23], h2_23, a);      \
    a = fmaf(w3[(o)*36+24], h2_24, a); a = fmaf(w3[(o)*36+25], h2_25, a);      \
    a = fmaf(w3[(o)*36+26], h2_26, a); a = fmaf(w3[(o)*36+27], h2_27, a);      \
    a = fmaf(w3[(o)*36+28], h2_28, a); a = fmaf(w3[(o)*36+29], h2_29, a);      \
    a = fmaf(w3[(o)*36+30], h2_30, a); a = fmaf(w3[(o)*36+31], h2_31, a);      \
    a = fmaf(w3[(o)*36+32], h2_32, a); a = fmaf(w3[(o)*36+33], h2_33, a);      \
    a = fmaf(w3[(o)*36+34], h2_34, a); a = fmaf(w3[(o)*36+35], h2_35, a);      \
    v = fmaf(w4[o], fmaxf(a, 0.0f), v); }
    R36(L34)
#undef L34

    int r = idx[m];
    int c = idx[MM + m];
    // high word = m+1 (unique, later m wins => numpy last-write-wins),
    // low word = value bits (payload only, never decides the compare)
    unsigned long long packed =
        ((unsigned long long)(unsigned)(m + 1) << 32) | (unsigned)__float_as_uint(v);
    atomicMax(&grid[r * NN + c], packed);
}

// ---------------- row max: one block per row --------------------------------
__global__ __launch_bounds__(256) void row_max_k(const unsigned long long* __restrict__ g,
                                                 float* __restrict__ out) {
    int r = blockIdx.x;
    float mx = SENTINEL;
    for (int c = threadIdx.x; c < NN; c += 256) {
        unsigned long long p = g[(size_t)r * NN + c];
        if (p) mx = fmaxf(mx, __uint_as_float((unsigned)p));
    }
    __shared__ float red[256];
    red[threadIdx.x] = mx;
    __syncthreads();
    for (int s = 128; s > 0; s >>= 1) {
        if (threadIdx.x < s) red[threadIdx.x] = fmaxf(red[threadIdx.x], red[threadIdx.x + s]);
        __syncthreads();
    }
    if (threadIdx.x == 0) out[r] = red[0];
}

// ---------------- col max: partials over row-chunks, then final -------------
#define CCHUNKS 25
#define CROWS   (KK / CCHUNKS)   // 40

__global__ __launch_bounds__(256) void col_partial(const unsigned long long* __restrict__ g,
                                                   float* __restrict__ part) {
    int n = blockIdx.x * 256 + threadIdx.x;
    if (n >= NN) return;
    int k0 = blockIdx.y * CROWS;
    float mx = SENTINEL;
    for (int k = k0; k < k0 + CROWS; ++k) {
        unsigned long long p = g[(size_t)k * NN + n];
        if (p) mx = fmaxf(mx, __uint_as_float((unsigned)p));
    }
    part[blockIdx.y * NN + n] = mx;
}

__global__ __launch_bounds__(256) void col_final(const float* __restrict__ part,
                                                 float* __restrict__ out) {
    int n = blockIdx.x * 256 + threadIdx.x;
    if (n >= NN) return;
    float mx = SENTINEL;
#pragma unroll
    for (int c = 0; c < CCHUNKS; ++c) mx = fmaxf(mx, part[c * NN + n]);
    out[KK + n] = mx;
}

extern "C" void kernel_launch(void* const* d_in, const int* in_sizes, int n_in,
                              void* d_out, int out_size, void* d_ws, size_t ws_size,
                              hipStream_t stream) {
    const float* in  = (const float*)d_in[0];
    // d_in[1] = T_out (zeros) — unused
    const int*   idx = (const int*)d_in[2];
    const float* w1  = (const float*)d_in[3];
    const float* b1  = (const float*)d_in[4];
    const float* w2  = (const float*)d_in[5];
    const float* b2  = (const float*)d_in[6];
    const float* w3  = (const float*)d_in[7];
    const float* b3  = (const float*)d_in[8];
    const float* w4  = (const float*)d_in[9];
    const float* b4  = (const float*)d_in[10];

    unsigned long long* grid = (unsigned long long*)d_ws;            // 8 MB
    float* part = (float*)((char*)d_ws + (size_t)KK * NN * 8);       // 100 KB
    float* out  = (float*)d_out;

    const int n2 = (KK * NN) / 2;  // ulonglong2 elements
    init_grid<<<(n2 + 255) / 256, 256, 0, stream>>>((ulonglong2*)grid, n2);

    mlp_scatter<<<(MM + 255) / 256, 256, 0, stream>>>(
        in, idx, w1, b1, w2, b2, w3, b3, w4, b4, grid);

    row_max_k<<<KK, 256, 0, stream>>>(grid, out);
    col_partial<<<dim3(4, CCHUNKS), 256, 0, stream>>>(grid, part);
    col_final<<<4, 256, 0, stream>>>(part, out);
}